// Round 6
// baseline (235.837 us; speedup 1.0000x reference)
//
#include <hip/hip_runtime.h>

// LIF spike scan: x[N, T=32] fp32, scan over contiguous T axis.
//   u = 0.25*u*(1-o_prev) + x_t ;  o = (u > 0.5) ? 1 : 0
// 0.25*u exact (pow2), (1-o) in {0,1} exact -> bit-exact vs numpy fp32 ref.
//
// R8 = R6 (zero-LDS, 4-lane/neuron register scan) + 4-chunk batching.
//  - R6/R7 post-mortem: store cache-policy is a proven no-op (FETCH byte-
//    identical under plain / builtin-nt / sc0-sc1-nt stores). Remaining
//    unprobed axis in the clean structure: per-wave MLP + scan-chain ILP.
//  - R6 loop = 2 loads -> ~350cy serial shuffle chain -> 2 stores -> next
//    loads: 2 KB outstanding/wave, next load gated behind the chain.
//    R8 issues 8 loads (4 consecutive chunks, 8 KB contiguous) up front,
//    runs 4 INDEPENDENT scan chains (4x ILP), then 8 stores. 4x MLP.
//  - If this is also ~82us: sync, LDS, occupancy, MLP, ILP, store policy
//    and access order are ALL exonerated by direct experiment -> the
//    mixed-R/W service rate with L3 write-allocate thrash is the ceiling.
//
// Chunk = 16 neurons x 32 T = 128 f4 = 2 KB. Group = 4 chunks = 8 KB.

constexpr float TAU = 0.25f;
constexpr float VTH = 0.5f;
constexpr int BLOCK = 256;
constexpr int GRID = 2048;
constexpr int BATCH = 4;                     // chunks per wave-iteration

typedef float f32x4 __attribute__((ext_vector_type(4)));

__global__ __launch_bounds__(BLOCK) void LIFSpike_kernel(
    const float* __restrict__ x, float* __restrict__ out, int n_groups) {
    const int t = threadIdx.x;
    const int lane = t & 63;
    const int j = lane & 3;                  // position within neuron group
    const int g = lane >> 2;                 // neuron group 0..15
    const int wave = blockIdx.x * (BLOCK / 64) + (t >> 6);
    const int nwaves = gridDim.x * (BLOCK / 64);

    const f32x4* __restrict__ xp = reinterpret_cast<const f32x4*>(x);
    f32x4* __restrict__ op = reinterpret_cast<f32x4*>(out);

    for (size_t grp = wave; grp < (size_t)n_groups; grp += nwaves) {
        const size_t gb = grp * (128 * BATCH);   // f4 units, 8 KB contiguous

        // Phase A: issue all 8 loads (4 chunks x 2 f4/lane) back-to-back.
        f32x4 v0[BATCH], v1[BATCH];
#pragma unroll
        for (int b = 0; b < BATCH; ++b) {
            const size_t a0 = gb + b * 128 + (size_t)g * 8 + j;
            v0[b] = xp[a0];
            v1[b] = xp[a0 + 4];
        }

        // Phase B: 4 independent serial scan chains (different neurons).
        f32x4 r0[BATCH], r1[BATCH];
#pragma unroll
        for (int b = 0; b < BATCH; ++b) {
            float u = 0.0f, o = 0.0f;
#pragma unroll
            for (int s = 0; s < 8; ++s) {
                if (j == (s & 3)) {          // owner of this 4-step segment
                    const f32x4 v = (s < 4) ? v0[b] : v1[b];
                    float uu = u, oo = o;
                    f32x4 r;
                    uu = TAU * uu * (1.0f - oo) + v.x;
                    oo = (uu > VTH) ? 1.0f : 0.0f;  r.x = oo;
                    uu = TAU * uu * (1.0f - oo) + v.y;
                    oo = (uu > VTH) ? 1.0f : 0.0f;  r.y = oo;
                    uu = TAU * uu * (1.0f - oo) + v.z;
                    oo = (uu > VTH) ? 1.0f : 0.0f;  r.z = oo;
                    uu = TAU * uu * (1.0f - oo) + v.w;
                    oo = (uu > VTH) ? 1.0f : 0.0f;  r.w = oo;
                    u = uu;
                    if (s < 4) r0[b] = r; else r1[b] = r;
                }
                // Broadcast owner's u to the 4-lane group; recompute o.
                u = __shfl(u, (lane & ~3) | (s & 3));
                o = (u > VTH) ? 1.0f : 0.0f;
            }
        }

        // Phase C: 8 stores back-to-back.
#pragma unroll
        for (int b = 0; b < BATCH; ++b) {
            const size_t a0 = gb + b * 128 + (size_t)g * 8 + j;
            op[a0] = r0[b];
            op[a0 + 4] = r1[b];
        }
    }
}

extern "C" void kernel_launch(void* const* d_in, const int* in_sizes, int n_in,
                              void* d_out, int out_size, void* d_ws, size_t ws_size,
                              hipStream_t stream) {
    const float* x = (const float*)d_in[0];
    float* out = (float*)d_out;
    int n_groups = in_sizes[0] / (512 * BATCH);  // 33,554,432 floats -> 16384
    LIFSpike_kernel<<<GRID, BLOCK, 0, stream>>>(x, out, n_groups);
}

// Round 7
// 228.029 us; speedup vs baseline: 1.0342x; 1.0342x over previous
//
#include <hip/hip_runtime.h>

// LIF spike scan: x[N, T=32] fp32, scan over contiguous T axis.
//   u = 0.25*u*(1-o_prev) + x_t ;  o = (u > 0.5) ? 1 : 0
// 0.25*u exact (pow2), (1-o) in {0,1} exact -> bit-exact vs numpy fp32 ref.
//
// R9 = R8 (zero-LDS, 4-lane/neuron, 4-chunk batch) + NON-TEMPORAL LOADS.
//  - Demand side fully exonerated (R0..R8: sync, LDS, occupancy 9-58%, MLP,
//    ILP, store policy, order -> all flat 80-85us @ ~2.4 TB/s HBM).
//  - Counter story: harness fill blit doesn't allocate L3 (FETCH=14KB) ->
//    input ~50% L3-resident steady-state (FETCH=65.5MB=49% every round).
//    HBM read-miss stream = sparse half-lines interleaved with hits + dense
//    write stream = DRAM page-locality worst case ~2.4 TB/s; m13's clean
//    dense copy = 6.29 TB/s. Demand changes can't fix a supply-side pattern.
//  - Untested lever: LOAD cache policy (R7 only tested stores). nt loads
//    that skip L3 allocation -> input reads become a dense sequential HBM
//    stream (FETCH -> ~131MB, the signature) and output gets L3 alone
//    (134MB < 256MB). Both streams dense = the copy-ubench regime.
//  - Manual s_waitcnt vmcnt(0) + sched_barrier(0) after the asm loads:
//    compiler doesn't track asm vmcnt, and register-only consumers can be
//    hoisted past an asm waitcnt despite "memory" (guide rule #18).

constexpr float TAU = 0.25f;
constexpr float VTH = 0.5f;
constexpr int BLOCK = 256;
constexpr int GRID = 2048;
constexpr int BATCH = 4;                     // chunks per wave-iteration

typedef float f32x4 __attribute__((ext_vector_type(4)));

__device__ __forceinline__ f32x4 load_nt(const f32x4* p) {
    f32x4 v;
    asm volatile("global_load_dwordx4 %0, %1, off sc0 sc1 nt"
                 : "=v"(v) : "v"(p) : "memory");
    return v;
}

__global__ __launch_bounds__(BLOCK) void LIFSpike_kernel(
    const float* __restrict__ x, float* __restrict__ out, int n_groups) {
    const int t = threadIdx.x;
    const int lane = t & 63;
    const int j = lane & 3;                  // position within neuron group
    const int g = lane >> 2;                 // neuron group 0..15
    const int wave = blockIdx.x * (BLOCK / 64) + (t >> 6);
    const int nwaves = gridDim.x * (BLOCK / 64);

    const f32x4* __restrict__ xp = reinterpret_cast<const f32x4*>(x);
    f32x4* __restrict__ op = reinterpret_cast<f32x4*>(out);

    for (size_t grp = wave; grp < (size_t)n_groups; grp += nwaves) {
        const size_t gb = grp * (128 * BATCH);   // f4 units, 8 KB contiguous

        // Phase A: issue all 8 nt-loads back-to-back, then one counted drain.
        f32x4 v0[BATCH], v1[BATCH];
#pragma unroll
        for (int b = 0; b < BATCH; ++b) {
            const size_t a0 = gb + b * 128 + (size_t)g * 8 + j;
            v0[b] = load_nt(xp + a0);
            v1[b] = load_nt(xp + a0 + 4);
        }
        asm volatile("s_waitcnt vmcnt(0)" ::: "memory");
        __builtin_amdgcn_sched_barrier(0);

        // Phase B: 4 independent serial scan chains (different neurons).
        f32x4 r0[BATCH], r1[BATCH];
#pragma unroll
        for (int b = 0; b < BATCH; ++b) {
            float u = 0.0f, o = 0.0f;
#pragma unroll
            for (int s = 0; s < 8; ++s) {
                if (j == (s & 3)) {          // owner of this 4-step segment
                    const f32x4 v = (s < 4) ? v0[b] : v1[b];
                    float uu = u, oo = o;
                    f32x4 r;
                    uu = TAU * uu * (1.0f - oo) + v.x;
                    oo = (uu > VTH) ? 1.0f : 0.0f;  r.x = oo;
                    uu = TAU * uu * (1.0f - oo) + v.y;
                    oo = (uu > VTH) ? 1.0f : 0.0f;  r.y = oo;
                    uu = TAU * uu * (1.0f - oo) + v.z;
                    oo = (uu > VTH) ? 1.0f : 0.0f;  r.z = oo;
                    uu = TAU * uu * (1.0f - oo) + v.w;
                    oo = (uu > VTH) ? 1.0f : 0.0f;  r.w = oo;
                    u = uu;
                    if (s < 4) r0[b] = r; else r1[b] = r;
                }
                // Broadcast owner's u to the 4-lane group; recompute o.
                u = __shfl(u, (lane & ~3) | (s & 3));
                o = (u > VTH) ? 1.0f : 0.0f;
            }
        }

        // Phase C: 8 plain stores back-to-back (store policy proven inert).
#pragma unroll
        for (int b = 0; b < BATCH; ++b) {
            const size_t a0 = gb + b * 128 + (size_t)g * 8 + j;
            op[a0] = r0[b];
            op[a0 + 4] = r1[b];
        }
    }
}

extern "C" void kernel_launch(void* const* d_in, const int* in_sizes, int n_in,
                              void* d_out, int out_size, void* d_ws, size_t ws_size,
                              hipStream_t stream) {
    const float* x = (const float*)d_in[0];
    float* out = (float*)d_out;
    int n_groups = in_sizes[0] / (512 * BATCH);  // 33,554,432 floats -> 16384
    LIFSpike_kernel<<<GRID, BLOCK, 0, stream>>>(x, out, n_groups);
}